// Round 7
// baseline (39.221 us; speedup 1.0000x reference)
//
#include <hip/hip_runtime.h>
#include <hip/hip_bf16.h>

typedef __attribute__((ext_vector_type(8))) short short8;
typedef __attribute__((ext_vector_type(4))) float floatx4;

#define B_ROWS 8192
#define DIM 128
#define NPAIR 4095
// rows scaled by sqrt(log2(e)) so S_mfma = S * log2(e) and exp(S) = exp2(S_mfma)
#define RSCALE 1.2011224087864498f

#define GLOAD_LDS16(gp, lp)                                                     \
    __builtin_amdgcn_global_load_lds(                                           \
        (const __attribute__((address_space(1))) void*)(gp),                    \
        (__attribute__((address_space(3))) void*)(lp), 16, 0, 0)

// ---------------- zero Z (fallback path only) ----------------
__global__ void kzero(float* __restrict__ Z) {
    int i = blockIdx.x * 256 + threadIdx.x;
    if (i < B_ROWS) Z[i] = 0.f;
}

// ------------- fused prep: normalize rows -> bf16 (scaled), pair dots, zero out -------------
__global__ void kprep(const float* __restrict__ X, __hip_bfloat16* __restrict__ XN,
                      float* __restrict__ pairT, float* __restrict__ out) {
    __shared__ float2 lds[4][64];
    const int wid = threadIdx.x >> 6;
    const int lane = threadIdx.x & 63;
    const int row = blockIdx.x * 4 + wid;

    const float2 v = *reinterpret_cast<const float2*>(X + row * DIM + lane * 2);
    float ss = v.x * v.x + v.y * v.y;
    #pragma unroll
    for (int m = 1; m < 64; m <<= 1) ss += __shfl_xor(ss, m, 64);
    const float rn = ss > 0.f ? rsqrtf(ss) : 0.f;
    const float2 nv = make_float2(v.x * rn, v.y * rn);

    *reinterpret_cast<__hip_bfloat162*>(XN + row * DIM + lane * 2) =
        __float22bfloat162_rn(make_float2(nv.x * RSCALE, nv.y * RSCALE));
    lds[wid][lane] = nv;  // unscaled for exact pair dot
    __syncthreads();

    if ((wid & 1) == 0) {
        const int p = blockIdx.x * 2 + (wid >> 1);
        if (p < NPAIR) {
            const float2 a = lds[wid][lane];
            const float2 b = lds[wid + 1][lane];
            float d = a.x * b.x + a.y * b.y;
            #pragma unroll
            for (int m = 1; m < 64; m <<= 1) d += __shfl_xor(d, m, 64);
            if (lane == 0) pairT[p] = d;
        }
    }
    if (blockIdx.x == 0 && threadIdx.x == 0) out[0] = 0.f;
}

// ---- stage one 64x128 bf16 half-tile to LDS (linear dest, pre-swizzled source) ----
// LDS[row][colL] = global[row][colL ^ ((row&7)<<3)]
__device__ __forceinline__ void stage_half(const __hip_bfloat16* __restrict__ gsrc,
                                           __hip_bfloat16* lbuf, int tid) {
    const int wid = tid >> 6;
    const int lane = tid & 63;
    #pragma unroll
    for (int it = 0; it < 4; ++it) {
        const int woff = it * 2048 + wid * 512;  // wave-uniform elem offset
        const int e = woff + lane * 8;
        const int src = (e & ~127) | ((e & 127) ^ (((e >> 7) & 7) << 3));
        GLOAD_LDS16(gsrc + src, lbuf + woff);
    }
}

// ------------- main: row-panel GEMM, A in regs, B half-tile dbuf LDS -------------
// grid (16, 64): y = row panel rb (128 rows), x = col group g (4 tiles of 128 cols).
// 4 waves 2x2: wave owns 64 rows; per phase, 32 of the 64 staged cols.
// 8 phases/block: phase t = (tile t>>1, half t&1), 16 KB staged per phase.
template <bool USEP>
__global__ void __launch_bounds__(256, 2) kgemm(const __hip_bfloat16* __restrict__ XN,
                                                float* __restrict__ ZP) {
    __shared__ __hip_bfloat16 Bs[2][64 * DIM];

    const int tid = threadIdx.x;
    const int wid = tid >> 6;
    const int lane = tid & 63;
    const int lr = lane & 15;
    const int lk = lane >> 4;
    const int wr = wid >> 1;
    const int wc = wid & 1;
    const int rb = blockIdx.y;
    const int g = blockIdx.x;

    // ---- A: 64 rows in registers: a[kk][m], rows rb*128 + wr*64 + m*16 + lr ----
    short8 a[4][4];
    const __hip_bfloat16* Abase = XN + (rb * 128 + wr * 64 + lr) * DIM + lk * 8;
    #pragma unroll
    for (int m = 0; m < 4; ++m)
        #pragma unroll
        for (int kk = 0; kk < 4; ++kk)
            a[kk][m] = *reinterpret_cast<const short8*>(Abase + m * 16 * DIM + kk * 32);

    float rp[4][4];
    #pragma unroll
    for (int m = 0; m < 4; ++m)
        #pragma unroll
        for (int r = 0; r < 4; ++r) rp[m][r] = 0.f;

    const floatx4 zero4 = {0.f, 0.f, 0.f, 0.f};

    // prologue: stage (tile 0, half 0)
    stage_half(XN + (g * 4) * 128 * DIM, Bs[0], tid);
    __syncthreads();

    #pragma unroll 2
    for (int t = 0; t < 8; ++t) {
        const int cur = t & 1;
        // issue next half-tile DMA first: overlaps this phase's ds_read + MFMA + exp
        if (t < 7) {
            const int nt = t + 1;
            stage_half(XN + ((g * 4 + (nt >> 1)) * 128 + (nt & 1) * 64) * DIM,
                       Bs[cur ^ 1], tid);
        }

        const int cbj = g * 4 + (t >> 1);
        // diagonal elements present only when this staged 64-col slab aligns with
        // this wave's 64-row slab of the diagonal tile
        const bool dzero = (cbj == rb) && ((t & 1) == wr);
        const __hip_bfloat16* Bt = Bs[cur];

        // B fragments: staged-local cols wc*32 + n*16 + lr, swizzled read
        short8 b[4][2];
        #pragma unroll
        for (int n = 0; n < 2; ++n) {
            const int row = wc * 32 + n * 16 + lr;
            #pragma unroll
            for (int kk = 0; kk < 4; ++kk) {
                const int col = (kk * 32 + lk * 8) ^ ((row & 7) << 3);
                b[kk][n] = *reinterpret_cast<const short8*>(&Bt[row * DIM + col]);
            }
        }

        floatx4 acc[4][2];
        #pragma unroll
        for (int m = 0; m < 4; ++m)
            #pragma unroll
            for (int n = 0; n < 2; ++n)
                acc[m][n] = __builtin_amdgcn_mfma_f32_16x16x32_bf16(a[0][m], b[0][n], zero4, 0, 0, 0);
        #pragma unroll
        for (int kk = 1; kk < 4; ++kk)
            #pragma unroll
            for (int m = 0; m < 4; ++m)
                #pragma unroll
                for (int n = 0; n < 2; ++n)
                    acc[m][n] = __builtin_amdgcn_mfma_f32_16x16x32_bf16(a[kk][m], b[kk][n], acc[m][n], 0, 0, 0);

        if (dzero) {
            #pragma unroll
            for (int m = 0; m < 4; ++m)
                #pragma unroll
                for (int n = 0; n < 2; ++n)
                    #pragma unroll
                    for (int r = 0; r < 4; ++r) {
                        float e = __builtin_amdgcn_exp2f(acc[m][n][r]);
                        if (m * 16 + lk * 4 + r == wc * 32 + n * 16 + lr) e = 0.f;
                        rp[m][r] += e;
                    }
        } else {
            #pragma unroll
            for (int m = 0; m < 4; ++m)
                #pragma unroll
                for (int n = 0; n < 2; ++n)
                    #pragma unroll
                    for (int r = 0; r < 4; ++r)
                        rp[m][r] += __builtin_amdgcn_exp2f(acc[m][n][r]);
        }
        // single barrier per phase: drains next-half DMA, orders buffer reuse
        __syncthreads();
    }

    // ---- row sums: reduce over lr, store slot (g*2 + wc) ----
    #pragma unroll
    for (int m = 0; m < 4; ++m)
        #pragma unroll
        for (int r = 0; r < 4; ++r) {
            float v = rp[m][r];
            v += __shfl_xor(v, 1, 64);
            v += __shfl_xor(v, 2, 64);
            v += __shfl_xor(v, 4, 64);
            v += __shfl_xor(v, 8, 64);
            if (lr == 0) {
                const int row = rb * 128 + wr * 64 + m * 16 + lk * 4 + r;
                if (USEP)
                    ZP[(g * 2 + wc) * B_ROWS + row] = v;
                else
                    atomicAdd(&ZP[row], v);
            }
        }
}

// ------------- final (P path): Z[r] = sum_{32 slots} P[t][r]; loss reduce -------------
__global__ void kfinalP(const float* __restrict__ P, const float* __restrict__ pairT,
                        float* __restrict__ out) {
    const int r = blockIdx.x * 256 + threadIdx.x;
    float s = 0.f;
    if (r < B_ROWS - 2) {
        float z = 0.f;
        #pragma unroll
        for (int tt = 0; tt < 32; ++tt) z += P[tt * B_ROWS + r];
        s = logf(z);
    }
    if (r < NPAIR) s -= 2.f * pairT[r];
    #pragma unroll
    for (int m = 1; m < 64; m <<= 1) s += __shfl_xor(s, m, 64);
    __shared__ float red[4];
    const int wid = threadIdx.x >> 6;
    const int lane = threadIdx.x & 63;
    if (lane == 0) red[wid] = s;
    __syncthreads();
    if (threadIdx.x == 0) {
        float tsum = red[0] + red[1] + red[2] + red[3];
        atomicAdd(out, tsum / (float)B_ROWS);
    }
}

// ------------- final (Z fallback path) -------------
__global__ void kfinalZ(const float* __restrict__ Z, const float* __restrict__ pairT,
                        float* __restrict__ out) {
    float s = 0.f;
    for (int r = threadIdx.x; r < B_ROWS - 2; r += 1024) s += logf(Z[r]);
    for (int p = threadIdx.x; p < NPAIR; p += 1024) s -= 2.f * pairT[p];
    #pragma unroll
    for (int m = 1; m < 64; m <<= 1) s += __shfl_xor(s, m, 64);
    __shared__ float red[16];
    const int wid = threadIdx.x >> 6;
    const int lane = threadIdx.x & 63;
    if (lane == 0) red[wid] = s;
    __syncthreads();
    if (threadIdx.x == 0) {
        float t = 0.f;
        #pragma unroll
        for (int i = 0; i < 16; ++i) t += red[i];
        out[0] = t / (float)B_ROWS;
    }
}

extern "C" void kernel_launch(void* const* d_in, const int* in_sizes, int n_in,
                              void* d_out, int out_size, void* d_ws, size_t ws_size,
                              hipStream_t stream) {
    (void)in_sizes; (void)n_in; (void)out_size;
    const float* X = (const float*)d_in[0];
    float* out = (float*)d_out;
    char* ws = (char*)d_ws;

    float* Z = (float*)ws;                                   // 32 KB
    float* pairT = (float*)(ws + 32768);                     // 16 KB
    __hip_bfloat16* XN = (__hip_bfloat16*)(ws + 49152);      // 2 MB
    float* P = (float*)(ws + 49152 + 2097152);               // 1 MB (32 x 8192 f32)
    const size_t need = 49152 + 2097152 + (size_t)32 * B_ROWS * 4;
    const bool useP = ws_size >= need;

    kprep<<<2048, 256, 0, stream>>>(X, XN, pairT, out);
    if (useP) {
        kgemm<true><<<dim3(16, 64), 256, 0, stream>>>(XN, P);
        kfinalP<<<32, 256, 0, stream>>>(P, pairT, out);
    } else {
        kzero<<<32, 256, 0, stream>>>(Z);
        kgemm<false><<<dim3(16, 64), 256, 0, stream>>>(XN, Z);
        kfinalZ<<<1, 1024, 0, stream>>>(Z, pairT, out);
    }
}

// Round 8
// 34.054 us; speedup vs baseline: 1.1517x; 1.1517x over previous
//
#include <hip/hip_runtime.h>
#include <hip/hip_bf16.h>

typedef __attribute__((ext_vector_type(8))) short short8;
typedef __attribute__((ext_vector_type(4))) float floatx4;

#define B_ROWS 8192
#define DIM 128
#define NPAIR 4095
// rows scaled by sqrt(log2(e)) so S_mfma = S * log2(e) and exp(S) = exp2(S_mfma)
#define RSCALE 1.2011224087864498f

#define GLOAD_LDS16(gp, lp)                                                     \
    __builtin_amdgcn_global_load_lds(                                           \
        (const __attribute__((address_space(1))) void*)(gp),                    \
        (__attribute__((address_space(3))) void*)(lp), 16, 0, 0)

// ---------------- zero Z (fallback path only) ----------------
__global__ void kzero(float* __restrict__ Z) {
    int i = blockIdx.x * 256 + threadIdx.x;
    if (i < B_ROWS) Z[i] = 0.f;
}

// ------------- fused prep: normalize rows -> bf16 (scaled), pair dots, zero out -------------
__global__ void kprep(const float* __restrict__ X, __hip_bfloat16* __restrict__ XN,
                      float* __restrict__ pairT, float* __restrict__ out) {
    __shared__ float2 lds[4][64];
    const int wid = threadIdx.x >> 6;
    const int lane = threadIdx.x & 63;
    const int row = blockIdx.x * 4 + wid;

    const float2 v = *reinterpret_cast<const float2*>(X + row * DIM + lane * 2);
    float ss = v.x * v.x + v.y * v.y;
    #pragma unroll
    for (int m = 1; m < 64; m <<= 1) ss += __shfl_xor(ss, m, 64);
    const float rn = ss > 0.f ? rsqrtf(ss) : 0.f;
    const float2 nv = make_float2(v.x * rn, v.y * rn);

    *reinterpret_cast<__hip_bfloat162*>(XN + row * DIM + lane * 2) =
        __float22bfloat162_rn(make_float2(nv.x * RSCALE, nv.y * RSCALE));
    lds[wid][lane] = nv;  // unscaled for exact pair dot
    __syncthreads();

    if ((wid & 1) == 0) {
        const int p = blockIdx.x * 2 + (wid >> 1);
        if (p < NPAIR) {
            const float2 a = lds[wid][lane];
            const float2 b = lds[wid + 1][lane];
            float d = a.x * b.x + a.y * b.y;
            #pragma unroll
            for (int m = 1; m < 64; m <<= 1) d += __shfl_xor(d, m, 64);
            if (lane == 0) pairT[p] = d;
        }
    }
    if (blockIdx.x == 0 && threadIdx.x == 0) out[0] = 0.f;
}

// ---- stage one 64x128 bf16 half-slab to LDS (linear dest, pre-swizzled source) ----
// LDS[row][colL] = global[row][colL ^ ((row&7)<<3)]; 4 DMA loads per thread.
__device__ __forceinline__ void stage_half(const __hip_bfloat16* __restrict__ gsrc,
                                           __hip_bfloat16* lbuf, int tid) {
    const int wid = tid >> 6;
    const int lane = tid & 63;
    #pragma unroll
    for (int it = 0; it < 4; ++it) {
        const int woff = it * 2048 + wid * 512;  // wave-uniform elem offset
        const int e = woff + lane * 8;
        const int src = (e & ~127) | ((e & 127) ^ (((e >> 7) & 7) << 3));
        GLOAD_LDS16(gsrc + src, lbuf + woff);
    }
}

// ------------- main: row-panel GEMM, A in regs, B 3-buffer counted-vmcnt pipeline -------------
// grid (8, 64): y = row panel rb (128 rows), x = col group g (8 tiles = 16 half-slabs).
// 4 waves 2x2: wave owns 64 rows x (32 cols of each staged 64-col slab).
// Phase t: wait vmcnt(4) [slab t landed; slab t+1 stays in flight] -> s_barrier ->
//          stage slab t+2 -> ds_read + MFMA + exp. One barrier/phase, never drains queue.
template <bool USEP>
__global__ void __launch_bounds__(256, 2) kgemm(const __hip_bfloat16* __restrict__ XN,
                                                float* __restrict__ ZP) {
    __shared__ __hip_bfloat16 Bs[3][64 * DIM];

    const int tid = threadIdx.x;
    const int wid = tid >> 6;
    const int lane = tid & 63;
    const int lr = lane & 15;
    const int lk = lane >> 4;
    const int wr = wid >> 1;
    const int wc = wid & 1;
    const int rb = blockIdx.y;
    const int g = blockIdx.x;

    // ---- A: 64 rows in registers: a[kk][m], rows rb*128 + wr*64 + m*16 + lr ----
    short8 a[4][4];
    const __hip_bfloat16* Abase = XN + (rb * 128 + wr * 64 + lr) * DIM + lk * 8;
    #pragma unroll
    for (int m = 0; m < 4; ++m)
        #pragma unroll
        for (int kk = 0; kk < 4; ++kk)
            a[kk][m] = *reinterpret_cast<const short8*>(Abase + m * 16 * DIM + kk * 32);

    float rp[4][4];
    #pragma unroll
    for (int m = 0; m < 4; ++m)
        #pragma unroll
        for (int r = 0; r < 4; ++r) rp[m][r] = 0.f;

    const floatx4 zero4 = {0.f, 0.f, 0.f, 0.f};

    // prologue: stage slabs 0 and 1 (slab s = tile g*8 + (s>>1), half s&1)
    stage_half(XN + (size_t)(g * 8) * 128 * DIM, Bs[0], tid);
    stage_half(XN + ((size_t)(g * 8) * 128 + 64) * DIM, Bs[1], tid);

    for (int t = 0; t < 16; ++t) {
        // counted wait: oldest outstanding slab (t) has landed; slab t+1 stays in flight
        if (t < 15)
            asm volatile("s_waitcnt vmcnt(4)" ::: "memory");
        else
            asm volatile("s_waitcnt vmcnt(0)" ::: "memory");
        __builtin_amdgcn_s_barrier();  // raw barrier: no vmcnt drain

        if (t + 2 < 16)
            stage_half(XN + ((size_t)(g * 8 + ((t + 2) >> 1)) * 128 + ((t + 2) & 1) * 64) * DIM,
                       Bs[(t + 2) % 3], tid);

        const __hip_bfloat16* Bt = Bs[t % 3];
        const int cbj = g * 8 + (t >> 1);
        const bool dzero = (cbj == rb) && ((t & 1) == wr);

        __builtin_amdgcn_s_setprio(1);
        // B fragments: staged-local cols wc*32 + n*16 + lr, swizzled read
        short8 b[4][2];
        #pragma unroll
        for (int n = 0; n < 2; ++n) {
            const int row = wc * 32 + n * 16 + lr;
            #pragma unroll
            for (int kk = 0; kk < 4; ++kk) {
                const int col = (kk * 32 + lk * 8) ^ ((row & 7) << 3);
                b[kk][n] = *reinterpret_cast<const short8*>(&Bt[row * DIM + col]);
            }
        }

        floatx4 acc[4][2];
        #pragma unroll
        for (int m = 0; m < 4; ++m)
            #pragma unroll
            for (int n = 0; n < 2; ++n)
                acc[m][n] = __builtin_amdgcn_mfma_f32_16x16x32_bf16(a[0][m], b[0][n], zero4, 0, 0, 0);
        #pragma unroll
        for (int kk = 1; kk < 4; ++kk)
            #pragma unroll
            for (int m = 0; m < 4; ++m)
                #pragma unroll
                for (int n = 0; n < 2; ++n)
                    acc[m][n] = __builtin_amdgcn_mfma_f32_16x16x32_bf16(a[kk][m], b[kk][n], acc[m][n], 0, 0, 0);
        __builtin_amdgcn_s_setprio(0);

        if (dzero) {
            #pragma unroll
            for (int m = 0; m < 4; ++m)
                #pragma unroll
                for (int n = 0; n < 2; ++n)
                    #pragma unroll
                    for (int r = 0; r < 4; ++r) {
                        float e = __builtin_amdgcn_exp2f(acc[m][n][r]);
                        if (m * 16 + lk * 4 + r == wc * 32 + n * 16 + lr) e = 0.f;
                        rp[m][r] += e;
                    }
        } else {
            #pragma unroll
            for (int m = 0; m < 4; ++m)
                #pragma unroll
                for (int n = 0; n < 2; ++n)
                    #pragma unroll
                    for (int r = 0; r < 4; ++r)
                        rp[m][r] += __builtin_amdgcn_exp2f(acc[m][n][r]);
        }
        // no trailing barrier: next phase's leading barrier provides the sync
    }

    // ---- row sums: reduce over lr, store slot (g*2 + wc) ----
    #pragma unroll
    for (int m = 0; m < 4; ++m)
        #pragma unroll
        for (int r = 0; r < 4; ++r) {
            float v = rp[m][r];
            v += __shfl_xor(v, 1, 64);
            v += __shfl_xor(v, 2, 64);
            v += __shfl_xor(v, 4, 64);
            v += __shfl_xor(v, 8, 64);
            if (lr == 0) {
                const int row = rb * 128 + wr * 64 + m * 16 + lk * 4 + r;
                if (USEP)
                    ZP[(g * 2 + wc) * B_ROWS + row] = v;
                else
                    atomicAdd(&ZP[row], v);
            }
        }
}

// ------------- final (P path): Z[r] = sum_{16 slots} P[t][r]; loss reduce -------------
__global__ void kfinalP(const float* __restrict__ P, const float* __restrict__ pairT,
                        float* __restrict__ out) {
    const int r = blockIdx.x * 256 + threadIdx.x;
    float s = 0.f;
    if (r < B_ROWS - 2) {
        float z = 0.f;
        #pragma unroll
        for (int tt = 0; tt < 16; ++tt) z += P[tt * B_ROWS + r];
        s = logf(z);
    }
    if (r < NPAIR) s -= 2.f * pairT[r];
    #pragma unroll
    for (int m = 1; m < 64; m <<= 1) s += __shfl_xor(s, m, 64);
    __shared__ float red[4];
    const int wid = threadIdx.x >> 6;
    const int lane = threadIdx.x & 63;
    if (lane == 0) red[wid] = s;
    __syncthreads();
    if (threadIdx.x == 0) {
        float tsum = red[0] + red[1] + red[2] + red[3];
        atomicAdd(out, tsum / (float)B_ROWS);
    }
}

// ------------- final (Z fallback path) -------------
__global__ void kfinalZ(const float* __restrict__ Z, const float* __restrict__ pairT,
                        float* __restrict__ out) {
    float s = 0.f;
    for (int r = threadIdx.x; r < B_ROWS - 2; r += 1024) s += logf(Z[r]);
    for (int p = threadIdx.x; p < NPAIR; p += 1024) s -= 2.f * pairT[p];
    #pragma unroll
    for (int m = 1; m < 64; m <<= 1) s += __shfl_xor(s, m, 64);
    __shared__ float red[16];
    const int wid = threadIdx.x >> 6;
    const int lane = threadIdx.x & 63;
    if (lane == 0) red[wid] = s;
    __syncthreads();
    if (threadIdx.x == 0) {
        float t = 0.f;
        #pragma unroll
        for (int i = 0; i < 16; ++i) t += red[i];
        out[0] = t / (float)B_ROWS;
    }
}

extern "C" void kernel_launch(void* const* d_in, const int* in_sizes, int n_in,
                              void* d_out, int out_size, void* d_ws, size_t ws_size,
                              hipStream_t stream) {
    (void)in_sizes; (void)n_in; (void)out_size;
    const float* X = (const float*)d_in[0];
    float* out = (float*)d_out;
    char* ws = (char*)d_ws;

    float* Z = (float*)ws;                                   // 32 KB
    float* pairT = (float*)(ws + 32768);                     // 16 KB
    __hip_bfloat16* XN = (__hip_bfloat16*)(ws + 49152);      // 2 MB
    float* P = (float*)(ws + 49152 + 2097152);               // 512 KB (16 x 8192 f32)
    const size_t need = 49152 + 2097152 + (size_t)16 * B_ROWS * 4;
    const bool useP = ws_size >= need;

    kprep<<<2048, 256, 0, stream>>>(X, XN, pairT, out);
    if (useP) {
        kgemm<true><<<dim3(8, 64), 256, 0, stream>>>(XN, P);
        kfinalP<<<32, 256, 0, stream>>>(P, pairT, out);
    } else {
        kzero<<<32, 256, 0, stream>>>(Z);
        kgemm<false><<<dim3(8, 64), 256, 0, stream>>>(XN, Z);
        kfinalZ<<<1, 1024, 0, stream>>>(Z, pairT, out);
    }
}